// Round 6
// baseline (498.820 us; speedup 1.0000x reference)
//
#include <hip/hip_runtime.h>

#define HXs 12   // padded x-stride
#define HYs 10
#define HZs 6
#define CST (HZs*HYs*HXs)      // 720 floats per channel
#define TILE_ELEMS (16*CST)    // 11520 floats = 46080 B

// LDS map (bytes):
//  [0,46080)      x-tile f32 [16][6][10][12]; reused (after sync2) as P bf16, 144B row stride
//  [46080,47104)  alive[256] f32
//  [47104,48128)  msu[256] f32  (smask*alive)

typedef __attribute__((ext_vector_type(8))) short bf16x8;
typedef __attribute__((ext_vector_type(4))) float f32x4;

__device__ __forceinline__ unsigned short f2bf(float f) {
    unsigned u = __builtin_bit_cast(unsigned, f);
    u += 0x7FFFu + ((u >> 16) & 1u);          // RNE
    return (unsigned short)(u >> 16);
}
__device__ __forceinline__ bf16x8 pack8f(float4 a, float4 b) {
    bf16x8 o;
    o[0] = (short)f2bf(a.x); o[1] = (short)f2bf(a.y);
    o[2] = (short)f2bf(a.z); o[3] = (short)f2bf(a.w);
    o[4] = (short)f2bf(b.x); o[5] = (short)f2bf(b.y);
    o[6] = (short)f2bf(b.z); o[7] = (short)f2bf(b.w);
    return o;
}

__global__ __launch_bounds__(256, 3) void nca_fused(
    const float* __restrict__ x, const float* __restrict__ rand_u,
    const float* __restrict__ w1, const float* __restrict__ b1,
    const float* __restrict__ w2, float* __restrict__ out)
{
    __shared__ __align__(16) char smem[48128];
    float*          tile   = (float*)smem;
    unsigned short* Ps     = (unsigned short*)smem;       // after sync2
    float*          aliveA = (float*)(smem + 46080);
    float*          msuA   = (float*)(smem + 47104);

    const int tid = threadIdx.x;
    const int gx0 = blockIdx.x * 8, gy0 = blockIdx.y * 8;
    const int zb  = blockIdx.z;
    const int b   = zb >> 4, gz0 = (zb & 15) * 4;
    const int xbase = b * (16 * 262144);

    // ---- phase 1: stage x tile (zero halo) ----
    for (int i = tid; i < TILE_ELEMS; i += 256) {
        int c = i / CST, r = i - c * CST;
        int z = r / (HYs * HXs), r2 = r - z * (HYs * HXs);
        int y = r2 / HXs, xx = r2 - y * HXs;
        int gz = gz0 + z - 1, gy = gy0 + y - 1, gxx = gx0 + xx - 1;
        float v = 0.f;
        if (xx < 10 && (unsigned)gz < 64u && (unsigned)gy < 64u && (unsigned)gxx < 64u)
            v = x[xbase + (c * 64 + gz) * 4096 + gy * 64 + gxx];
        tile[i] = v;
    }
    __syncthreads();

    // ---- phase 2: perception (fp32 VALU) ----
    const int tx = tid & 7, ty = (tid >> 3) & 7, tz = tid >> 6;
    const int lane = tid & 63, wv = tid >> 6;
    const int g = lane >> 4, r16 = lane & 15;

    float p[64];
    float pool3 = -1e30f;
    #pragma unroll
    for (int c = 0; c < 16; ++c) {
        float s1 = 0.f, s2 = 0.f, s3 = 0.f;
        #pragma unroll
        for (int i = 0; i < 3; ++i) {
            const float di = (i == 0) ? -1.f : ((i == 2) ? 1.f : 0.f);
            const float gi = (i == 1) ? 2.f : 1.f;
            #pragma unroll
            for (int j = 0; j < 3; ++j) {
                const float dj = (j == 0) ? -1.f : ((j == 2) ? 1.f : 0.f);
                const float gj = (j == 1) ? 2.f : 1.f;
                #pragma unroll
                for (int k = 0; k < 3; ++k) {
                    const float dk = (k == 0) ? -1.f : ((k == 2) ? 1.f : 0.f);
                    const float gk = (k == 1) ? 2.f : 1.f;
                    float v = tile[((c * HZs + tz + i) * HYs + ty + j) * HXs + tx + k];
                    s1 = fmaf(di * gj * gk, v, s1);
                    s2 = fmaf(gi * dj * gk, v, s2);
                    s3 = fmaf(gi * gj * dk, v, s3);
                    if (c == 3) pool3 = fmaxf(pool3, v);
                }
            }
        }
        p[4 * c + 0] = tile[((c * HZs + tz + 1) * HYs + ty + 1) * HXs + tx + 1];
        p[4 * c + 1] = s1 * 0.125f;
        p[4 * c + 2] = s2 * 0.125f;
        p[4 * c + 3] = s3 * 0.125f;
    }
    const float alive = (pool3 > 0.1f) ? 1.f : 0.f;
    const float ru = rand_u[b * 262144 + (gz0 + tz) * 4096 + (gy0 + ty) * 64 + (gx0 + tx)];
    aliveA[tid] = alive;
    msuA[tid]   = (ru <= 0.5f) ? alive : 0.f;

    // epilogue-x prefetch from LDS tile (exact fp32), before tile is overwritten
    float xa[16];
    #pragma unroll
    for (int n = 0; n < 4; ++n) {
        int vy = 2 * n + (r16 >> 3), vx = r16 & 7;
        #pragma unroll
        for (int reg = 0; reg < 4; ++reg) {
            int c = 4 * g + reg;
            xa[4 * n + reg] = tile[((c * HZs + wv + 1) * HYs + vy + 1) * HXs + vx + 1];
        }
    }
    __syncthreads();   // all waves done reading tile

    // ---- phase 3: write P (bf16) over the tile region ----
    unsigned pk[32];
    #pragma unroll
    for (int q2 = 0; q2 < 32; ++q2)
        pk[q2] = (unsigned)f2bf(p[2 * q2]) | ((unsigned)f2bf(p[2 * q2 + 1]) << 16);
    uint4* prow = (uint4*)(smem + tid * 144);
    #pragma unroll
    for (int j = 0; j < 8; ++j)
        prow[j] = make_uint4(pk[4 * j], pk[4 * j + 1], pk[4 * j + 2], pk[4 * j + 3]);
    __syncthreads();   // P visible to all waves

    // ---- phase 4: MFMA, 2 n-halves to cap live registers ----
    const f32x4 z4 = {0,0,0,0};
    const int rbase = 8 * (r16 >> 2) + (r16 & 3);   // even frag row within 32-block

    #pragma unroll
    for (int half = 0; half < 2; ++half) {
        // P B-fragments for this half's 2 n-tiles (LDS persists)
        bf16x8 pf[2][2];
        #pragma unroll
        for (int nn = 0; nn < 2; ++nn) {
            int v = (4 * wv + 2 * half + nn) * 16 + r16;
            #pragma unroll
            for (int ks = 0; ks < 2; ++ks)
                pf[nn][ks] = *(const bf16x8*)(Ps + v * 72 + ks * 32 + g * 8);
        }

        f32x4 acc2[2] = {{0,0,0,0},{0,0,0,0}};

        #pragma unroll
        for (int ch = 0; ch < 4; ++ch) {
            // W1/W2 fragments straight from global (L1/L2-hot), f2bf pack
            const float* wE = w1 + (ch * 32 + rbase) * 64 + g * 8;
            const float* wO = wE + 4 * 64;
            bf16x8 aE0 = pack8f(*(const float4*)(wE),      *(const float4*)(wE + 4));
            bf16x8 aE1 = pack8f(*(const float4*)(wE + 32), *(const float4*)(wE + 36));
            bf16x8 aO0 = pack8f(*(const float4*)(wO),      *(const float4*)(wO + 4));
            bf16x8 aO1 = pack8f(*(const float4*)(wO + 32), *(const float4*)(wO + 36));
            const float* w2p = w2 + r16 * 128 + ch * 32 + g * 8;
            bf16x8 w2f = pack8f(*(const float4*)(w2p), *(const float4*)(w2p + 4));
            float4 bE = *(const float4*)(b1 + ch * 32 + 8 * g);
            float4 bO = *(const float4*)(b1 + ch * 32 + 8 * g + 4);

            #pragma unroll
            for (int nn = 0; nn < 2; ++nn) {
                f32x4 accE, accO;
                accE = __builtin_amdgcn_mfma_f32_16x16x32_bf16(aE0, pf[nn][0], z4, 0, 0, 0);
                accE = __builtin_amdgcn_mfma_f32_16x16x32_bf16(aE1, pf[nn][1], accE, 0, 0, 0);
                accO = __builtin_amdgcn_mfma_f32_16x16x32_bf16(aO0, pf[nn][0], z4, 0, 0, 0);
                accO = __builtin_amdgcn_mfma_f32_16x16x32_bf16(aO1, pf[nn][1], accO, 0, 0, 0);
                bf16x8 hb;
                hb[0] = (short)f2bf(fmaxf(accE[0] + bE.x, 0.f));
                hb[1] = (short)f2bf(fmaxf(accE[1] + bE.y, 0.f));
                hb[2] = (short)f2bf(fmaxf(accE[2] + bE.z, 0.f));
                hb[3] = (short)f2bf(fmaxf(accE[3] + bE.w, 0.f));
                hb[4] = (short)f2bf(fmaxf(accO[0] + bO.x, 0.f));
                hb[5] = (short)f2bf(fmaxf(accO[1] + bO.y, 0.f));
                hb[6] = (short)f2bf(fmaxf(accO[2] + bO.z, 0.f));
                hb[7] = (short)f2bf(fmaxf(accO[3] + bO.w, 0.f));
                acc2[nn] = __builtin_amdgcn_mfma_f32_16x16x32_bf16(w2f, hb, acc2[nn], 0, 0, 0);
            }
        }

        // ---- epilogue for this half: out = x*alive + upd*(smask*alive) ----
        #pragma unroll
        for (int nn = 0; nn < 2; ++nn) {
            int n = 2 * half + nn;
            int v = (4 * wv + n) * 16 + r16;
            float al = aliveA[v], mu = msuA[v];
            int vx = v & 7, vy = (v >> 3) & 7;
            int gidx = xbase + (gz0 + wv) * 4096 + (gy0 + vy) * 64 + (gx0 + vx);
            #pragma unroll
            for (int reg = 0; reg < 4; ++reg) {
                int c = 4 * g + reg;
                out[gidx + c * 262144] = xa[4 * n + reg] * al + acc2[nn][reg] * mu;
            }
        }
    }
}

extern "C" void kernel_launch(void* const* d_in, const int* in_sizes, int n_in,
                              void* d_out, int out_size, void* d_ws, size_t ws_size,
                              hipStream_t stream)
{
    const float* x      = (const float*)d_in[0];
    const float* rand_u = (const float*)d_in[1];
    const float* w1     = (const float*)d_in[2];
    const float* b1     = (const float*)d_in[3];
    const float* w2     = (const float*)d_in[4];
    float* out = (float*)d_out;

    dim3 grid(8, 8, 64);
    dim3 block(256);
    nca_fused<<<grid, block, 0, stream>>>(x, rand_u, w1, b1, w2, out);
}

// Round 7
// 223.145 us; speedup vs baseline: 2.2354x; 2.2354x over previous
//
#include <hip/hip_runtime.h>

#define HXs 12   // padded x-stride
#define HYs 10
#define HZs 6
#define CST (HZs*HYs*HXs)      // 720 floats per channel
#define TILE_ELEMS (16*CST)    // 11520 floats = 46080 B

// LDS map (bytes):
//  [0,46080)      x-tile f32 [16][6][10][12]; reused (after sync2) as P bf16, 144B row stride
//  [46080,47104)  alive[256] f32
//  [47104,48128)  msu[256] f32  (smask*alive)
//
// d_ws map (shorts): [0,8192) W1 frags: 1024 x 16B, entry w -> (ch=w>>8, f=(w>>6)&3, lane=w&63)
//                    [8192,10240) W2 frags: 256 x 16B, entry w -> (ch=w>>6, lane=w&63)

typedef __attribute__((ext_vector_type(8))) short bf16x8;
typedef __attribute__((ext_vector_type(4))) float f32x4;

__device__ __forceinline__ unsigned short f2bf(float f) {
    unsigned u = __builtin_bit_cast(unsigned, f);
    u += 0x7FFFu + ((u >> 16) & 1u);          // RNE
    return (unsigned short)(u >> 16);
}
__device__ __forceinline__ bf16x8 pack8f(float4 a, float4 b) {
    bf16x8 o;
    o[0] = (short)f2bf(a.x); o[1] = (short)f2bf(a.y);
    o[2] = (short)f2bf(a.z); o[3] = (short)f2bf(a.w);
    o[4] = (short)f2bf(b.x); o[5] = (short)f2bf(b.y);
    o[6] = (short)f2bf(b.z); o[7] = (short)f2bf(b.w);
    return o;
}

// ---- pre-pass: permute W1/W2 into lane-canonical bf16 MFMA fragments in d_ws ----
__global__ __launch_bounds__(256) void permute_w(
    const float* __restrict__ w1, const float* __restrict__ w2,
    unsigned short* __restrict__ wsW)
{
    const int t = threadIdx.x;
    #pragma unroll
    for (int j = 0; j < 4; ++j) {
        int w = t + 256 * j;                 // [0,1024)
        int lane = w & 63, f = (w >> 6) & 3, ch = w >> 8;
        int r16 = lane & 15, g = lane >> 4;
        int row = ch * 32 + 8 * (r16 >> 2) + (r16 & 3) + 4 * (f >> 1);  // E: +0, O: +4
        int col = (f & 1) * 32 + g * 8;                                  // ks half
        const float* src = w1 + row * 64 + col;
        bf16x8 v = pack8f(*(const float4*)src, *(const float4*)(src + 4));
        *(bf16x8*)(wsW + w * 8) = v;
    }
    {
        int w = t;                           // [0,256)
        int lane = w & 63, ch = w >> 6;
        int r16 = lane & 15, g = lane >> 4;
        const float* src = w2 + r16 * 128 + ch * 32 + g * 8;
        bf16x8 v = pack8f(*(const float4*)src, *(const float4*)(src + 4));
        *(bf16x8*)(wsW + 8192 + w * 8) = v;
    }
}

__global__ __launch_bounds__(256, 3) void nca_fused(
    const float* __restrict__ x, const float* __restrict__ rand_u,
    const unsigned short* __restrict__ wsW, const float* __restrict__ b1,
    float* __restrict__ out)
{
    __shared__ __align__(16) char smem[48128];
    float*          tile   = (float*)smem;
    unsigned short* Ps     = (unsigned short*)smem;       // after sync2
    float*          aliveA = (float*)(smem + 46080);
    float*          msuA   = (float*)(smem + 47104);

    const int tid = threadIdx.x;
    const int gx0 = blockIdx.x * 8, gy0 = blockIdx.y * 8;
    const int zb  = blockIdx.z;
    const int b   = zb >> 4, gz0 = (zb & 15) * 4;
    const int xbase = b * (16 * 262144);

    // ---- phase 1: stage x tile (zero halo) ----
    for (int i = tid; i < TILE_ELEMS; i += 256) {
        int c = i / CST, r = i - c * CST;
        int z = r / (HYs * HXs), r2 = r - z * (HYs * HXs);
        int y = r2 / HXs, xx = r2 - y * HXs;
        int gz = gz0 + z - 1, gy = gy0 + y - 1, gxx = gx0 + xx - 1;
        float v = 0.f;
        if (xx < 10 && (unsigned)gz < 64u && (unsigned)gy < 64u && (unsigned)gxx < 64u)
            v = x[xbase + (c * 64 + gz) * 4096 + gy * 64 + gxx];
        tile[i] = v;
    }
    __syncthreads();

    // ---- phase 2: perception (fp32 VALU), packing p->bf16 per channel ----
    const int tx = tid & 7, ty = (tid >> 3) & 7, tz = tid >> 6;
    const int lane = tid & 63, wv = tid >> 6;
    const int g = lane >> 4, r16 = lane & 15;

    unsigned pk[32];
    float pool3 = -1e30f;
    #pragma unroll
    for (int c = 0; c < 16; ++c) {
        float s1 = 0.f, s2 = 0.f, s3 = 0.f;
        #pragma unroll
        for (int i = 0; i < 3; ++i) {
            const float di = (i == 0) ? -1.f : ((i == 2) ? 1.f : 0.f);
            const float gi = (i == 1) ? 2.f : 1.f;
            #pragma unroll
            for (int j = 0; j < 3; ++j) {
                const float dj = (j == 0) ? -1.f : ((j == 2) ? 1.f : 0.f);
                const float gj = (j == 1) ? 2.f : 1.f;
                #pragma unroll
                for (int k = 0; k < 3; ++k) {
                    const float dk = (k == 0) ? -1.f : ((k == 2) ? 1.f : 0.f);
                    const float gk = (k == 1) ? 2.f : 1.f;
                    float v = tile[((c * HZs + tz + i) * HYs + ty + j) * HXs + tx + k];
                    s1 = fmaf(di * gj * gk, v, s1);
                    s2 = fmaf(gi * dj * gk, v, s2);
                    s3 = fmaf(gi * gj * dk, v, s3);
                    if (c == 3) pool3 = fmaxf(pool3, v);
                }
            }
        }
        float ctr = tile[((c * HZs + tz + 1) * HYs + ty + 1) * HXs + tx + 1];
        pk[2 * c]     = (unsigned)f2bf(ctr)          | ((unsigned)f2bf(s1 * 0.125f) << 16);
        pk[2 * c + 1] = (unsigned)f2bf(s2 * 0.125f)  | ((unsigned)f2bf(s3 * 0.125f) << 16);
    }
    const float alive = (pool3 > 0.1f) ? 1.f : 0.f;
    const float ru = rand_u[b * 262144 + (gz0 + tz) * 4096 + (gy0 + ty) * 64 + (gx0 + tx)];
    aliveA[tid] = alive;
    msuA[tid]   = (ru <= 0.5f) ? alive : 0.f;
    __syncthreads();   // all waves done reading tile

    // ---- phase 3: write P (bf16) over the tile region ----
    uint4* prow = (uint4*)(smem + tid * 144);
    #pragma unroll
    for (int j = 0; j < 8; ++j)
        prow[j] = make_uint4(pk[4 * j], pk[4 * j + 1], pk[4 * j + 2], pk[4 * j + 3]);
    __syncthreads();   // P visible to all waves

    // ---- phase 4: MFMA. GEMM1: h^T = W1p . P^T ; GEMM2: upd^T = W2 . h^T ----
    bf16x8 pf[4][2];
    #pragma unroll
    for (int n = 0; n < 4; ++n) {
        int v = (4 * wv + n) * 16 + r16;
        #pragma unroll
        for (int ks = 0; ks < 2; ++ks)
            pf[n][ks] = *(const bf16x8*)(Ps + v * 72 + ks * 32 + g * 8);
    }

    f32x4 acc2[4] = {{0,0,0,0},{0,0,0,0},{0,0,0,0},{0,0,0,0}};
    const f32x4 z4 = {0,0,0,0};

    #pragma unroll
    for (int ch = 0; ch < 4; ++ch) {
        // lane-canonical bf16 fragments, prepermuted by permute_w (L1-hot 20KB)
        const bf16x8 aE0 = *(const bf16x8*)(wsW + ((ch * 4 + 0) * 64 + lane) * 8);
        const bf16x8 aE1 = *(const bf16x8*)(wsW + ((ch * 4 + 1) * 64 + lane) * 8);
        const bf16x8 aO0 = *(const bf16x8*)(wsW + ((ch * 4 + 2) * 64 + lane) * 8);
        const bf16x8 aO1 = *(const bf16x8*)(wsW + ((ch * 4 + 3) * 64 + lane) * 8);
        const bf16x8 w2f = *(const bf16x8*)(wsW + 8192 + (ch * 64 + lane) * 8);
        const float4 bE = *(const float4*)(b1 + ch * 32 + 8 * g);
        const float4 bO = *(const float4*)(b1 + ch * 32 + 8 * g + 4);

        #pragma unroll
        for (int n = 0; n < 4; ++n) {
            f32x4 accE, accO;
            accE = __builtin_amdgcn_mfma_f32_16x16x32_bf16(aE0, pf[n][0], z4, 0, 0, 0);
            accE = __builtin_amdgcn_mfma_f32_16x16x32_bf16(aE1, pf[n][1], accE, 0, 0, 0);
            accO = __builtin_amdgcn_mfma_f32_16x16x32_bf16(aO0, pf[n][0], z4, 0, 0, 0);
            accO = __builtin_amdgcn_mfma_f32_16x16x32_bf16(aO1, pf[n][1], accO, 0, 0, 0);
            bf16x8 hb;
            hb[0] = (short)f2bf(fmaxf(accE[0] + bE.x, 0.f));
            hb[1] = (short)f2bf(fmaxf(accE[1] + bE.y, 0.f));
            hb[2] = (short)f2bf(fmaxf(accE[2] + bE.z, 0.f));
            hb[3] = (short)f2bf(fmaxf(accE[3] + bE.w, 0.f));
            hb[4] = (short)f2bf(fmaxf(accO[0] + bO.x, 0.f));
            hb[5] = (short)f2bf(fmaxf(accO[1] + bO.y, 0.f));
            hb[6] = (short)f2bf(fmaxf(accO[2] + bO.z, 0.f));
            hb[7] = (short)f2bf(fmaxf(accO[3] + bO.w, 0.f));
            acc2[n] = __builtin_amdgcn_mfma_f32_16x16x32_bf16(w2f, hb, acc2[n], 0, 0, 0);
        }
    }

    // ---- phase 5: epilogue: out = x*alive + upd*(smask*alive), x re-read (coalesced) ----
    #pragma unroll
    for (int n = 0; n < 4; ++n) {
        int v = (4 * wv + n) * 16 + r16;
        float al = aliveA[v], mu = msuA[v];
        int vx = v & 7, vy = (v >> 3) & 7;
        int gidx = xbase + (gz0 + wv) * 4096 + (gy0 + vy) * 64 + (gx0 + vx);
        #pragma unroll
        for (int reg = 0; reg < 4; ++reg) {
            int c = 4 * g + reg;
            int idx = gidx + c * 262144;
            out[idx] = x[idx] * al + acc2[n][reg] * mu;
        }
    }
}

extern "C" void kernel_launch(void* const* d_in, const int* in_sizes, int n_in,
                              void* d_out, int out_size, void* d_ws, size_t ws_size,
                              hipStream_t stream)
{
    const float* x      = (const float*)d_in[0];
    const float* rand_u = (const float*)d_in[1];
    const float* w1     = (const float*)d_in[2];
    const float* b1     = (const float*)d_in[3];
    const float* w2     = (const float*)d_in[4];
    float* out = (float*)d_out;
    unsigned short* wsW = (unsigned short*)d_ws;   // 20.5 KB used

    permute_w<<<dim3(1), dim3(256), 0, stream>>>(w1, w2, wsW);

    dim3 grid(8, 8, 64);
    dim3 block(256);
    nca_fused<<<grid, block, 0, stream>>>(x, rand_u, wsW, b1, out);
}